// Round 3
// baseline (156.821 us; speedup 1.0000x reference)
//
#include <hip/hip_runtime.h>
#include <hip/hip_bf16.h>
#include <cstdio>

typedef float f32x4 __attribute__((ext_vector_type(4)));
typedef __bf16 bf16x8 __attribute__((ext_vector_type(8)));

static constexpr int Bn = 8, Nn = 2048, Dn = 512, Hn = 512;

__device__ __forceinline__ unsigned short f2bf(float x) {
    union { float f; unsigned int u; } v; v.f = x;
    unsigned int r = (v.u + 0x7FFFu + ((v.u >> 16) & 1u)) >> 16;
    return (unsigned short)r;
}
__device__ __forceinline__ float bf2f(unsigned short h) {
    union { unsigned int u; float f; } v; v.u = ((unsigned int)h) << 16;
    return v.f;
}

__device__ __forceinline__ void gload_lds16(const unsigned short* g, unsigned short* l) {
    __builtin_amdgcn_global_load_lds(
        (const __attribute__((address_space(1))) void*)g,
        (__attribute__((address_space(3))) void*)l,
        16, 0, 0);
}

__device__ __forceinline__ int xcd_swizzle(int lin, int nwg) {
    return (lin & 7) * (nwg >> 3) + (lin >> 3);   // all grids %8==0
}

// ---------------- cast x (f32 -> bf16), flat ----------------
__global__ void cast_x_kernel(const float* __restrict__ x, unsigned short* __restrict__ xb, int n) {
    int i = (blockIdx.x * blockDim.x + threadIdx.x) * 8;
    if (i >= n) return;
    float4 a = *(const float4*)(x + i);
    float4 b = *(const float4*)(x + i + 4);
    unsigned short tmp[8] = {f2bf(a.x), f2bf(a.y), f2bf(a.z), f2bf(a.w),
                             f2bf(b.x), f2bf(b.y), f2bf(b.z), f2bf(b.w)};
    *(uint4*)(xb + i) = *(const uint4*)tmp;
}

// ---- transpose + cast (+ optional per-input-row divide): in f32 [R][C] -> out bf16 [C][R] ----
__global__ __launch_bounds__(256) void transpose_cast_kernel(
    const float* __restrict__ in, unsigned short* __restrict__ out,
    const float* __restrict__ sdiv, int R, int C)
{
    __shared__ float tile[64][65];
    const int z = blockIdx.z;
    const float* inb = in + (size_t)z * R * C;
    unsigned short* outb = out + (size_t)z * R * C;
    const int r0 = blockIdx.y * 64, c0 = blockIdx.x * 64;
    const int tx = threadIdx.x & 63, ty = threadIdx.x >> 6;
#pragma unroll
    for (int p = 0; p < 64; p += 4) {
        const int r = p + ty;
        float v = inb[(size_t)(r0 + r) * C + c0 + tx];
        if (sdiv) v /= sdiv[(size_t)z * R + r0 + r];
        tile[r][tx] = v;
    }
    __syncthreads();
#pragma unroll
    for (int p = 0; p < 64; p += 4) {
        const int oc = p + ty;
        outb[(size_t)(c0 + oc) * R + r0 + tx] = f2bf(tile[tx][oc]);
    }
}

// ---------------- combine per-block partial column sums ----------------
__global__ void combine_s_kernel(const float* __restrict__ s_part, float* __restrict__ s,
                                 int nblk, int total) {
    int i = blockIdx.x * blockDim.x + threadIdx.x;
    if (i >= total) return;
    int z = i >> 11, j = i & (Nn - 1);
    float acc = 0.f;
    for (int p = 0; p < nblk; ++p) acc += s_part[((size_t)z * nblk + p) * Nn + j];
    s[i] = acc;
}

// ============ 256x256 8-phase GEMM (C = A * B^T), K-half-sliced LDS ring ============
// A: [M][lda] bf16 (+z*sA), Bt: [N][ldb] bf16 (+z*sB). BK=64, 8 waves (2x4).
// LDS per operand: 4 slots of 256rows x 32k (slot = (T&1)*2 + kh). 128 KiB total.
// Per phase: {8|4|8|4} ds_read_b128, stage 1 half-tile (2 gload_lds), vmcnt(4)+barrier
// at kh boundaries only (vmcnt(0) only at last tile's kh1), setprio around 16 MFMA.
// Read swizzle within each 1KB region: slot = l15*4 + (g ^ ((l15>>1)&3)) — verified
// bijection; max 2-way bank aliasing (free). Stage source pre-permuted to match.
// MODE 0: C bf16 [M][N], bias split (col<bsplit ? bias : bias2)
// MODE 1: C bf16 = exp(acc), + per-column partial sums s_part[z][gy][Nn]
template<int MODE>
__global__ __launch_bounds__(512, 2) void gemm8p(
    const unsigned short* __restrict__ A, long long sA, int lda,
    const unsigned short* __restrict__ Bt, long long sB, int ldb,
    void* __restrict__ Cp, long long sC,
    const float* __restrict__ bias, const float* __restrict__ bias2, int bsplit,
    float* __restrict__ s_part,
    int M, int N, int K, int gx, int gy)
{
    __shared__ unsigned short As[4][8192];   // 64 KB
    __shared__ unsigned short Bs[4][8192];   // 64 KB

    const int lin = xcd_swizzle(blockIdx.x, gridDim.x);
    const int bz = lin / (gx * gy);
    const int rem = lin - bz * gx * gy;
    const int by = rem / gx;
    const int bx = rem - by * gx;

    const unsigned short* Ab = A + (size_t)bz * sA;
    const unsigned short* Bb = Bt + (size_t)bz * sB;
    const int i0 = by * 256, j0 = bx * 256;

    const int t = threadIdx.x;
    const int lane = t & 63;
    const int w = t >> 6;              // wave 0..7
    const int wm = w >> 2, wn = w & 3; // 2 x 4 wave grid; per-wave C = 128 x 64
    const int l15 = lane & 15, g = lane >> 4;

    // read: byte offset of this lane's b128 within a 1KB (16-row) region
    const int rd_off = (l15 * 4 + (g ^ ((l15 >> 1) & 3))) * 16;
    // stage: lane -> global (row, k) pre-permutation (inverse of read swizzle)
    const int grow = lane >> 2;                         // 0..15
    const int gk = ((lane & 3) ^ ((lane >> 3) & 3)) * 8;

    f32x4 acc[8][4];
    const f32x4 zero4 = {0.f, 0.f, 0.f, 0.f};
#pragma unroll
    for (int mi = 0; mi < 8; ++mi)
#pragma unroll
        for (int nf = 0; nf < 4; ++nf) acc[mi][nf] = zero4;

    const int NT = K >> 6;

    // stage one half-tile (256 rows x 32 k) of tile Tn, k-half kh: 2 instrs/wave
#define STAGE(baseP, ldP, r0P, ldsP, Tn, kh)                                             \
    {                                                                                    \
        const int _slot = ((Tn) & 1) * 2 + (kh);                                         \
        const unsigned short* _src = (baseP) + (size_t)((r0P) + w * 16 + grow) * (ldP)   \
                                     + (Tn) * 64 + (kh) * 32 + gk;                       \
        gload_lds16(_src, &ldsP[_slot][w * 512]);                                        \
        gload_lds16(_src + (size_t)128 * (ldP), &ldsP[_slot][(w + 8) * 512]);            \
    }

    // prologue: tile 0, order A-kh0, B-kh0, A-kh1, B-kh1  (8 loads/wave)
    STAGE(Ab, lda, i0, As, 0, 0);
    STAGE(Bb, ldb, j0, Bs, 0, 0);
    STAGE(Ab, lda, i0, As, 0, 1);
    STAGE(Bb, ldb, j0, Bs, 0, 1);

    bf16x8 bfv[4];   // persistent B frags across mh phases

    for (int T = 0; T < NT; ++T) {
        const int sbase = (T & 1) * 2;
        const bool last = (T == NT - 1);
#pragma unroll
        for (int q = 0; q < 4; ++q) {
            const int kk = q >> 1, mh = q & 1;
            if (q == 0) {
                asm volatile("s_waitcnt vmcnt(4)" ::: "memory");
                asm volatile("s_barrier" ::: "memory");
            } else if (q == 2) {
                if (last) asm volatile("s_waitcnt vmcnt(0)" ::: "memory");
                else      asm volatile("s_waitcnt vmcnt(4)" ::: "memory");
                asm volatile("s_barrier" ::: "memory");
            }
            // ds reads: B frags only at kh boundary (held in regs for mh=1 phase)
            const char* Bbase = (const char*)&Bs[sbase + kk][0] + (wn * 4) * 1024 + rd_off;
            if (mh == 0) {
#pragma unroll
                for (int nf = 0; nf < 4; ++nf)
                    bfv[nf] = *(const bf16x8*)(Bbase + nf * 1024);
            }
            const char* Abase = (const char*)&As[sbase + kk][0] + (wm * 8 + mh * 4) * 1024 + rd_off;
            bf16x8 af[4];
#pragma unroll
            for (int mf = 0; mf < 4; ++mf)
                af[mf] = *(const bf16x8*)(Abase + mf * 1024);
            // stage next tile's half (1 per phase)
            if (!last) {
                if (q == 0)      STAGE(Ab, lda, i0, As, T + 1, 0)
                else if (q == 1) STAGE(Bb, ldb, j0, Bs, T + 1, 0)
                else if (q == 2) STAGE(Ab, lda, i0, As, T + 1, 1)
                else             STAGE(Bb, ldb, j0, Bs, T + 1, 1)
            }
            __builtin_amdgcn_s_setprio(1);
#pragma unroll
            for (int mf = 0; mf < 4; ++mf)
#pragma unroll
                for (int nf = 0; nf < 4; ++nf)
                    acc[mh * 4 + mf][nf] =
                        __builtin_amdgcn_mfma_f32_16x16x32_bf16(af[mf], bfv[nf], acc[mh * 4 + mf][nf], 0, 0, 0);
            __builtin_amdgcn_s_setprio(0);
            asm volatile("s_barrier" ::: "memory");
        }
    }
#undef STAGE

    if (MODE == 0) {
        unsigned short* C = (unsigned short*)Cp;
#pragma unroll
        for (int nf = 0; nf < 4; ++nf) {
            const int col = j0 + wn * 64 + nf * 16 + l15;
            const float bv = (col < bsplit) ? bias[col] : bias2[col - bsplit];
#pragma unroll
            for (int mi = 0; mi < 8; ++mi) {
                const int rb = i0 + wm * 128 + (mi >> 2) * 64 + (mi & 3) * 16 + g * 4;
#pragma unroll
                for (int r = 0; r < 4; ++r)
                    C[(size_t)(rb + r) * N + col] = f2bf(acc[mi][nf][r] + bv);
            }
        }
    } else {
        unsigned short* C = (unsigned short*)Cp + (size_t)bz * sC;
        float cs[4] = {0.f, 0.f, 0.f, 0.f};
#pragma unroll
        for (int nf = 0; nf < 4; ++nf) {
            const int col = j0 + wn * 64 + nf * 16 + l15;
#pragma unroll
            for (int mi = 0; mi < 8; ++mi) {
                const int rb = i0 + wm * 128 + (mi >> 2) * 64 + (mi & 3) * 16 + g * 4;
#pragma unroll
                for (int r = 0; r < 4; ++r) {
                    const float e = __expf(acc[mi][nf][r]);
                    const unsigned short h = f2bf(e);
                    C[(size_t)(rb + r) * N + col] = h;
                    cs[nf] += bf2f(h);   // sum rounded value: num/denom consistency
                }
            }
        }
#pragma unroll
        for (int nf = 0; nf < 4; ++nf) {
            cs[nf] += __shfl_xor(cs[nf], 16);
            cs[nf] += __shfl_xor(cs[nf], 32);
        }
        __syncthreads();
        float* red = (float*)&As[0][0];   // reuse LDS: [2][256]
        if (g == 0) {
#pragma unroll
            for (int nf = 0; nf < 4; ++nf)
                red[wm * 256 + wn * 64 + nf * 16 + l15] = cs[nf];
        }
        __syncthreads();
        if (t < 256)
            s_part[((size_t)bz * gy + by) * Nn + j0 + t] = red[t] + red[256 + t];
    }
}

// ---------------- 128x128 2-barrier GEMM (kept for PV: MODE 2, f32 out) ----------------
template<int MODE>
__global__ __launch_bounds__(256, 2) void gemm_bt(
    const unsigned short* __restrict__ A, long long sA, int lda,
    const unsigned short* __restrict__ Bt, long long sB, int ldb,
    void* __restrict__ Cp, long long sC,
    int M, int N, int K, int gx, int gy)
{
    __shared__ unsigned short As[128 * 64];
    __shared__ unsigned short Bs[128 * 64];

    const int lin = xcd_swizzle(blockIdx.x, gridDim.x);
    const int bz = lin / (gx * gy);
    const int rem = lin - bz * gx * gy;
    const int by = rem / gx;
    const int bx = rem - by * gx;

    const unsigned short* Ab = A + (size_t)bz * sA;
    const unsigned short* Bb = Bt + (size_t)bz * sB;
    const int i0 = by * 128, j0 = bx * 128;

    const int t = threadIdx.x;
    const int lane = t & 63;
    const int wave = t >> 6;
    const int wr = wave >> 1, wc = wave & 1;
    const int l15 = lane & 15, g = lane >> 4;

    f32x4 acc[4][4];
    const f32x4 zero4 = {0.f, 0.f, 0.f, 0.f};
#pragma unroll
    for (int mi = 0; mi < 4; ++mi)
#pragma unroll
        for (int ni = 0; ni < 4; ++ni) acc[mi][ni] = zero4;

    const int rbase = wave * 32;
    const int lrow = lane >> 3;
    const int gch = (lane & 7) ^ lrow;

    for (int kt = 0; kt < K; kt += 64) {
#pragma unroll
        for (int i = 0; i < 4; ++i) {
            const int r = rbase + i * 8 + lrow;
            gload_lds16(Ab + (size_t)(i0 + r) * lda + kt + gch * 8, As + (rbase + i * 8) * 64);
            gload_lds16(Bb + (size_t)(j0 + r) * ldb + kt + gch * 8, Bs + (rbase + i * 8) * 64);
        }
        __syncthreads();
#pragma unroll
        for (int kk = 0; kk < 64; kk += 32) {
            const int sl0 = (kk >> 3) + g;
            bf16x8 af[4], bfr[4];
#pragma unroll
            for (int mi = 0; mi < 4; ++mi) {
                const int row = wr * 64 + mi * 16 + l15;
                af[mi] = *(const bf16x8*)(As + row * 64 + ((sl0 ^ (row & 7)) * 8));
            }
#pragma unroll
            for (int ni = 0; ni < 4; ++ni) {
                const int row = wc * 64 + ni * 16 + l15;
                bfr[ni] = *(const bf16x8*)(Bs + row * 64 + ((sl0 ^ (row & 7)) * 8));
            }
#pragma unroll
            for (int mi = 0; mi < 4; ++mi)
#pragma unroll
                for (int ni = 0; ni < 4; ++ni)
                    acc[mi][ni] = __builtin_amdgcn_mfma_f32_16x16x32_bf16(af[mi], bfr[ni], acc[mi][ni], 0, 0, 0);
        }
        __syncthreads();
    }

    float* C = (float*)Cp + (size_t)bz * sC;
#pragma unroll
    for (int ni = 0; ni < 4; ++ni) {
        const int col = j0 + wc * 64 + ni * 16 + l15;
#pragma unroll
        for (int mi = 0; mi < 4; ++mi) {
            const int rb = i0 + wr * 64 + mi * 16 + g * 4;
#pragma unroll
            for (int r = 0; r < 4; ++r)
                C[(size_t)(rb + r) * N + col] = acc[mi][ni][r];
        }
    }
}

extern "C" void kernel_launch(void* const* d_in, const int* in_sizes, int n_in,
                              void* d_out, int out_size, void* d_ws, size_t ws_size,
                              hipStream_t stream) {
    const float* x  = (const float*)d_in[0];
    const float* Wq = (const float*)d_in[1];
    const float* bq = (const float*)d_in[2];
    const float* Wk = (const float*)d_in[3];
    const float* bk = (const float*)d_in[4];
    float* out = (float*)d_out;

    char* ws = (char*)d_ws;
    unsigned short* xb    = (unsigned short*)(ws);                               // 16 MB
    unsigned short* qk    = (unsigned short*)(ws + (16ull << 20));               // 32 MB [16384][1024]
    unsigned short* WqkT  = (unsigned short*)(ws + (48ull << 20));               // 1 MB [1024][512]
    unsigned short* xsT   = (unsigned short*)(ws + (49ull << 20));               // 16 MB
    float*          s_prt = (float*)(ws + (65ull << 20));                        // 1 MB
    float*          s     = (float*)(ws + (66ull << 20));                        // 64 KB
    unsigned short* expE  = (unsigned short*)(ws + (67ull << 20));               // 64 MB
    if (ws_size < (131ull << 20)) {
        fprintf(stderr, "WS TOO SMALL: have %zu need %llu\n", ws_size, (131ull << 20));
    }

    // 1) xb = bf16(x)
    cast_x_kernel<<<dim3((Bn * Nn * Dn) / (8 * 256)), 256, 0, stream>>>(x, xb, Bn * Nn * Dn);
    // 2) WqkT = bf16([Wq; Wk]^T)  -> [1024][512]
    transpose_cast_kernel<<<dim3(Hn / 64, Dn / 64, 1), 256, 0, stream>>>(Wq, WqkT, nullptr, Dn, Hn);
    transpose_cast_kernel<<<dim3(Hn / 64, Dn / 64, 1), 256, 0, stream>>>(Wk, WqkT + (size_t)Hn * Dn, nullptr, Dn, Hn);
    // 3) qk = xb @ [Wq|Wk] + [bq|bk]   (M=16384, N=1024, K=512) — 64 x 4 = 256 blocks
    {
        const int gx = (2 * Hn) / 256, gy = (Bn * Nn) / 256;
        gemm8p<0><<<dim3(gx * gy), 512, 0, stream>>>(
            xb, 0, Dn, WqkT, 0, Dn, qk, 0, bq, bk, Hn, nullptr,
            Bn * Nn, 2 * Hn, Dn, gx, gy);
    }
    // 4) expE = exp(q @ k^T), s_part (per batch; M=N=2048, K=512) — 8 x 8 x 8 = 512 blocks
    {
        const int gx = Nn / 256, gy = Nn / 256;
        gemm8p<1><<<dim3(gx * gy * Bn), 512, 0, stream>>>(
            qk, (long long)Nn * 2 * Hn, 2 * Hn,               // q = qk[:, 0:512]
            qk + Hn, (long long)Nn * 2 * Hn, 2 * Hn,          // k = qk[:, 512:1024]
            expE, (long long)Nn * Nn, nullptr, nullptr, 0, s_prt,
            Nn, Nn, Hn, gx, gy);
    }
    // 5) s[b][j] = sum of partials (8 m-blocks per batch now)
    combine_s_kernel<<<dim3((Bn * Nn) / 256), 256, 0, stream>>>(s_prt, s, Nn / 256, Bn * Nn);
    // 6) xsT[b][d][j] = bf16(x[b][j][d] / s[b][j])
    transpose_cast_kernel<<<dim3(Dn / 64, Nn / 64, Bn), 256, 0, stream>>>(x, xsT, s, Nn, Dn);
    // 7) out = expE @ xsT^T   (per batch; M=2048, N=512, K=2048) — 4 x 16 x 8 = 512 blocks
    {
        const int gx = Dn / 128, gy = Nn / 128;
        gemm_bt<2><<<dim3(gx * gy * Bn), 256, 0, stream>>>(
            expE, (long long)Nn * Nn, Nn, xsT, (long long)Dn * Nn, Nn,
            out, (long long)Nn * Dn, Nn, Dn, Nn, gx, gy);
    }
}

// Round 4
// 144.161 us; speedup vs baseline: 1.0878x; 1.0878x over previous
//
#include <hip/hip_runtime.h>
#include <hip/hip_bf16.h>
#include <cstdio>

typedef float f32x4 __attribute__((ext_vector_type(4)));
typedef __bf16 bf16x8 __attribute__((ext_vector_type(8)));

static constexpr int Bn = 8, Nn = 2048, Dn = 512, Hn = 512;

__device__ __forceinline__ unsigned short f2bf(float x) {
    union { float f; unsigned int u; } v; v.f = x;
    unsigned int r = (v.u + 0x7FFFu + ((v.u >> 16) & 1u)) >> 16;
    return (unsigned short)r;
}
__device__ __forceinline__ float bf2f(unsigned short h) {
    union { unsigned int u; float f; } v; v.u = ((unsigned int)h) << 16;
    return v.f;
}

__device__ __forceinline__ void gload_lds16(const unsigned short* g, unsigned short* l) {
    __builtin_amdgcn_global_load_lds(
        (const __attribute__((address_space(1))) void*)g,
        (__attribute__((address_space(3))) void*)l,
        16, 0, 0);
}

__device__ __forceinline__ int xcd_swizzle(int lin, int nwg) {
    return (lin & 7) * (nwg >> 3) + (lin >> 3);   // all grids %8==0
}

// ---------------- cast x (f32 -> bf16), flat ----------------
__global__ void cast_x_kernel(const float* __restrict__ x, unsigned short* __restrict__ xb, int n) {
    int i = (blockIdx.x * blockDim.x + threadIdx.x) * 8;
    if (i >= n) return;
    float4 a = *(const float4*)(x + i);
    float4 b = *(const float4*)(x + i + 4);
    unsigned short tmp[8] = {f2bf(a.x), f2bf(a.y), f2bf(a.z), f2bf(a.w),
                             f2bf(b.x), f2bf(b.y), f2bf(b.z), f2bf(b.w)};
    *(uint4*)(xb + i) = *(const uint4*)tmp;
}

// ---- transpose + cast (+ optional per-input-row divide): in f32 [R][C] -> out bf16 [C][R] ----
__global__ __launch_bounds__(256) void transpose_cast_kernel(
    const float* __restrict__ in, unsigned short* __restrict__ out,
    const float* __restrict__ sdiv, int R, int C)
{
    __shared__ float tile[64][65];
    const int z = blockIdx.z;
    const float* inb = in + (size_t)z * R * C;
    unsigned short* outb = out + (size_t)z * R * C;
    const int r0 = blockIdx.y * 64, c0 = blockIdx.x * 64;
    const int tx = threadIdx.x & 63, ty = threadIdx.x >> 6;
#pragma unroll
    for (int p = 0; p < 64; p += 4) {
        const int r = p + ty;
        float v = inb[(size_t)(r0 + r) * C + c0 + tx];
        if (sdiv) v /= sdiv[(size_t)z * R + r0 + r];
        tile[r][tx] = v;
    }
    __syncthreads();
#pragma unroll
    for (int p = 0; p < 64; p += 4) {
        const int oc = p + ty;
        outb[(size_t)(c0 + oc) * R + r0 + tx] = f2bf(tile[tx][oc]);
    }
}

// ---------------- combine per-block partial column sums ----------------
__global__ void combine_s_kernel(const float* __restrict__ s_part, float* __restrict__ s,
                                 int nblk, int total) {
    int i = blockIdx.x * blockDim.x + threadIdx.x;
    if (i >= total) return;
    int z = i >> 11, j = i & (Nn - 1);
    float acc = 0.f;
    for (int p = 0; p < nblk; ++p) acc += s_part[((size_t)z * nblk + p) * Nn + j];
    s[i] = acc;
}

// ============ 256x256 8-phase GEMM (C = A * B^T), K-half-sliced LDS ring ============
// Schedule (R4): per K-tile only TWO sync points (vmcnt(4)+s_barrier at each kh
// boundary; vmcnt(0) only at last tile's kh1). No trailing barriers: staging
// targets the opposite slot-pair, and the kh barriers bound wave drift so the
// last readers of any slot are >=1 full barrier behind any writer of it.
// Per phase: ds_read frags -> stage 1 half-tile (2 gload_lds) -> setprio(1) 16 MFMA.
// MODE 0: C bf16 [M][N], bias split (col<bsplit ? bias : bias2)
// MODE 1: C bf16 = exp(acc), + per-column partial sums s_part[z][gy][Nn]
// Epilogue stores: nf innermost so consecutive 32B chunks of one row issue
// back-to-back (64B-line merge; R3 had 2x write amplification without this).
template<int MODE>
__global__ __launch_bounds__(512, 2) void gemm8p(
    const unsigned short* __restrict__ A, long long sA, int lda,
    const unsigned short* __restrict__ Bt, long long sB, int ldb,
    void* __restrict__ Cp, long long sC,
    const float* __restrict__ bias, const float* __restrict__ bias2, int bsplit,
    float* __restrict__ s_part,
    int M, int N, int K, int gx, int gy)
{
    __shared__ unsigned short As[4][8192];   // 64 KB
    __shared__ unsigned short Bs[4][8192];   // 64 KB

    const int lin = xcd_swizzle(blockIdx.x, gridDim.x);
    const int bz = lin / (gx * gy);
    const int rem = lin - bz * gx * gy;
    const int by = rem / gx;
    const int bx = rem - by * gx;

    const unsigned short* Ab = A + (size_t)bz * sA;
    const unsigned short* Bb = Bt + (size_t)bz * sB;
    const int i0 = by * 256, j0 = bx * 256;

    const int t = threadIdx.x;
    const int lane = t & 63;
    const int w = t >> 6;              // wave 0..7
    const int wm = w >> 2, wn = w & 3; // 2 x 4 wave grid; per-wave C = 128 x 64
    const int l15 = lane & 15, g = lane >> 4;

    // read: byte offset of this lane's b128 within a 1KB (16-row) region
    const int rd_off = (l15 * 4 + (g ^ ((l15 >> 1) & 3))) * 16;
    // stage: lane -> global (row, k) pre-permutation (inverse of read swizzle)
    const int grow = lane >> 2;                         // 0..15
    const int gk = ((lane & 3) ^ ((lane >> 3) & 3)) * 8;

    f32x4 acc[8][4];
    const f32x4 zero4 = {0.f, 0.f, 0.f, 0.f};
#pragma unroll
    for (int mi = 0; mi < 8; ++mi)
#pragma unroll
        for (int nf = 0; nf < 4; ++nf) acc[mi][nf] = zero4;

    const int NT = K >> 6;

#define STAGE(baseP, ldP, r0P, ldsP, Tn, kh)                                             \
    {                                                                                    \
        const int _slot = ((Tn) & 1) * 2 + (kh);                                         \
        const unsigned short* _src = (baseP) + (size_t)((r0P) + w * 16 + grow) * (ldP)   \
                                     + (Tn) * 64 + (kh) * 32 + gk;                       \
        gload_lds16(_src, &ldsP[_slot][w * 512]);                                        \
        gload_lds16(_src + (size_t)128 * (ldP), &ldsP[_slot][(w + 8) * 512]);            \
    }

    // prologue: tile 0, order A-kh0, B-kh0, A-kh1, B-kh1  (8 loads/wave)
    STAGE(Ab, lda, i0, As, 0, 0);
    STAGE(Bb, ldb, j0, Bs, 0, 0);
    STAGE(Ab, lda, i0, As, 0, 1);
    STAGE(Bb, ldb, j0, Bs, 0, 1);

    for (int T = 0; T < NT; ++T) {
        const int sbase = (T & 1) * 2;
        const bool last = (T == NT - 1);

        // ------- kh = 0 -------
        asm volatile("s_waitcnt vmcnt(4)" ::: "memory");
        asm volatile("s_barrier" ::: "memory");
        {
            const char* Bbase = (const char*)&Bs[sbase][0] + wn * 4096 + rd_off;
            const char* Abase = (const char*)&As[sbase][0] + wm * 8192 + rd_off;
            bf16x8 bfv[4], af[4];
#pragma unroll
            for (int nf = 0; nf < 4; ++nf) bfv[nf] = *(const bf16x8*)(Bbase + nf * 1024);
#pragma unroll
            for (int mf = 0; mf < 4; ++mf) af[mf] = *(const bf16x8*)(Abase + mf * 1024);
            if (!last) STAGE(Ab, lda, i0, As, T + 1, 0);
            __builtin_amdgcn_s_setprio(1);
#pragma unroll
            for (int mf = 0; mf < 4; ++mf)
#pragma unroll
                for (int nf = 0; nf < 4; ++nf)
                    acc[mf][nf] = __builtin_amdgcn_mfma_f32_16x16x32_bf16(af[mf], bfv[nf], acc[mf][nf], 0, 0, 0);
            __builtin_amdgcn_s_setprio(0);
            // phase mh=1
            bf16x8 ag[4];
#pragma unroll
            for (int mf = 0; mf < 4; ++mf) ag[mf] = *(const bf16x8*)(Abase + 4096 + mf * 1024);
            if (!last) STAGE(Bb, ldb, j0, Bs, T + 1, 0);
            __builtin_amdgcn_s_setprio(1);
#pragma unroll
            for (int mf = 0; mf < 4; ++mf)
#pragma unroll
                for (int nf = 0; nf < 4; ++nf)
                    acc[4 + mf][nf] = __builtin_amdgcn_mfma_f32_16x16x32_bf16(ag[mf], bfv[nf], acc[4 + mf][nf], 0, 0, 0);
            __builtin_amdgcn_s_setprio(0);
        }

        // ------- kh = 1 -------
        if (last) asm volatile("s_waitcnt vmcnt(0)" ::: "memory");
        else      asm volatile("s_waitcnt vmcnt(4)" ::: "memory");
        asm volatile("s_barrier" ::: "memory");
        {
            const char* Bbase = (const char*)&Bs[sbase + 1][0] + wn * 4096 + rd_off;
            const char* Abase = (const char*)&As[sbase + 1][0] + wm * 8192 + rd_off;
            bf16x8 bfv[4], af[4];
#pragma unroll
            for (int nf = 0; nf < 4; ++nf) bfv[nf] = *(const bf16x8*)(Bbase + nf * 1024);
#pragma unroll
            for (int mf = 0; mf < 4; ++mf) af[mf] = *(const bf16x8*)(Abase + mf * 1024);
            if (!last) STAGE(Ab, lda, i0, As, T + 1, 1);
            __builtin_amdgcn_s_setprio(1);
#pragma unroll
            for (int mf = 0; mf < 4; ++mf)
#pragma unroll
                for (int nf = 0; nf < 4; ++nf)
                    acc[mf][nf] = __builtin_amdgcn_mfma_f32_16x16x32_bf16(af[mf], bfv[nf], acc[mf][nf], 0, 0, 0);
            __builtin_amdgcn_s_setprio(0);
            // phase mh=1
            bf16x8 ag[4];
#pragma unroll
            for (int mf = 0; mf < 4; ++mf) ag[mf] = *(const bf16x8*)(Abase + 4096 + mf * 1024);
            if (!last) STAGE(Bb, ldb, j0, Bs, T + 1, 1);
            __builtin_amdgcn_s_setprio(1);
#pragma unroll
            for (int mf = 0; mf < 4; ++mf)
#pragma unroll
                for (int nf = 0; nf < 4; ++nf)
                    acc[4 + mf][nf] = __builtin_amdgcn_mfma_f32_16x16x32_bf16(ag[mf], bfv[nf], acc[4 + mf][nf], 0, 0, 0);
            __builtin_amdgcn_s_setprio(0);
        }
    }
#undef STAGE

    if (MODE == 0) {
        unsigned short* C = (unsigned short*)Cp;
        float bv[4];
#pragma unroll
        for (int nf = 0; nf < 4; ++nf) {
            const int col = j0 + wn * 64 + nf * 16 + l15;
            bv[nf] = (col < bsplit) ? bias[col] : bias2[col - bsplit];
        }
        const int col0 = j0 + wn * 64 + l15;
#pragma unroll
        for (int mi = 0; mi < 8; ++mi) {
            const int rb = i0 + wm * 128 + (mi >> 2) * 64 + (mi & 3) * 16 + g * 4;
#pragma unroll
            for (int r = 0; r < 4; ++r) {
                unsigned short* Crow = C + (size_t)(rb + r) * N + col0;
#pragma unroll
                for (int nf = 0; nf < 4; ++nf)
                    Crow[nf * 16] = f2bf(acc[mi][nf][r] + bv[nf]);
            }
        }
    } else {
        unsigned short* C = (unsigned short*)Cp + (size_t)bz * sC;
        float cs[4] = {0.f, 0.f, 0.f, 0.f};
        const int col0 = j0 + wn * 64 + l15;
#pragma unroll
        for (int mi = 0; mi < 8; ++mi) {
            const int rb = i0 + wm * 128 + (mi >> 2) * 64 + (mi & 3) * 16 + g * 4;
#pragma unroll
            for (int r = 0; r < 4; ++r) {
                unsigned short* Crow = C + (size_t)(rb + r) * N + col0;
#pragma unroll
                for (int nf = 0; nf < 4; ++nf) {
                    const float e = __expf(acc[mi][nf][r]);
                    const unsigned short h = f2bf(e);
                    Crow[nf * 16] = h;
                    cs[nf] += bf2f(h);   // sum rounded value: num/denom consistency
                }
            }
        }
#pragma unroll
        for (int nf = 0; nf < 4; ++nf) {
            cs[nf] += __shfl_xor(cs[nf], 16);
            cs[nf] += __shfl_xor(cs[nf], 32);
        }
        __syncthreads();
        float* red = (float*)&As[0][0];   // [2][256]
        if (g == 0) {
#pragma unroll
            for (int nf = 0; nf < 4; ++nf)
                red[wm * 256 + wn * 64 + nf * 16 + l15] = cs[nf];
        }
        __syncthreads();
        if (t < 256)
            s_part[((size_t)bz * gy + by) * Nn + j0 + t] = red[t] + red[256 + t];
    }
}

// ------- 128x128 double-buffered 2-phase GEMM for PV (f32 out) -------
// Catalog T3-minimum recipe: STAGE(buf^1, T+1) issued BEFORE reads/MFMA of
// buf[cur]; single vmcnt(0)+s_barrier per K-tile. 64 KB LDS -> 2 blocks/CU.
__global__ __launch_bounds__(256, 2) void gemm_pv(
    const unsigned short* __restrict__ A, long long sA, int lda,
    const unsigned short* __restrict__ Bt, long long sB, int ldb,
    float* __restrict__ Cp, long long sC,
    int M, int N, int K, int gx, int gy)
{
    __shared__ unsigned short As[2][128 * 64];
    __shared__ unsigned short Bs[2][128 * 64];

    const int lin = xcd_swizzle(blockIdx.x, gridDim.x);
    const int bz = lin / (gx * gy);
    const int rem = lin - bz * gx * gy;
    const int by = rem / gx;
    const int bx = rem - by * gx;

    const unsigned short* Ab = A + (size_t)bz * sA;
    const unsigned short* Bb = Bt + (size_t)bz * sB;
    const int i0 = by * 128, j0 = bx * 128;

    const int t = threadIdx.x;
    const int lane = t & 63;
    const int wave = t >> 6;
    const int wr = wave >> 1, wc = wave & 1;
    const int l15 = lane & 15, g = lane >> 4;

    f32x4 acc[4][4];
    const f32x4 zero4 = {0.f, 0.f, 0.f, 0.f};
#pragma unroll
    for (int mi = 0; mi < 4; ++mi)
#pragma unroll
        for (int ni = 0; ni < 4; ++ni) acc[mi][ni] = zero4;

    const int rbase = wave * 32;
    const int lrow = lane >> 3;
    const int gch = (lane & 7) ^ lrow;

#define STAGEPV(s, ktv)                                                        \
    {                                                                          \
        _Pragma("unroll")                                                      \
        for (int i = 0; i < 4; ++i) {                                          \
            const int r = rbase + i * 8 + lrow;                                \
            gload_lds16(Ab + (size_t)(i0 + r) * lda + (ktv) + gch * 8,         \
                        &As[s][(rbase + i * 8) * 64]);                         \
            gload_lds16(Bb + (size_t)(j0 + r) * ldb + (ktv) + gch * 8,         \
                        &Bs[s][(rbase + i * 8) * 64]);                         \
        }                                                                      \
    }

    STAGEPV(0, 0);
    asm volatile("s_waitcnt vmcnt(0)" ::: "memory");
    asm volatile("s_barrier" ::: "memory");

    const int NT = K >> 6;
    for (int T = 0; T < NT; ++T) {
        const int cur = T & 1;
        if (T + 1 < NT) STAGEPV(cur ^ 1, (T + 1) * 64);
#pragma unroll
        for (int kk = 0; kk < 64; kk += 32) {
            const int sl0 = (kk >> 3) + g;
            bf16x8 af[4], bfr[4];
#pragma unroll
            for (int mi = 0; mi < 4; ++mi) {
                const int row = wr * 64 + mi * 16 + l15;
                af[mi] = *(const bf16x8*)(&As[cur][0] + row * 64 + ((sl0 ^ (row & 7)) * 8));
            }
#pragma unroll
            for (int ni = 0; ni < 4; ++ni) {
                const int row = wc * 64 + ni * 16 + l15;
                bfr[ni] = *(const bf16x8*)(&Bs[cur][0] + row * 64 + ((sl0 ^ (row & 7)) * 8));
            }
            __builtin_amdgcn_s_setprio(1);
#pragma unroll
            for (int mi = 0; mi < 4; ++mi)
#pragma unroll
                for (int ni = 0; ni < 4; ++ni)
                    acc[mi][ni] = __builtin_amdgcn_mfma_f32_16x16x32_bf16(af[mi], bfr[ni], acc[mi][ni], 0, 0, 0);
            __builtin_amdgcn_s_setprio(0);
        }
        asm volatile("s_waitcnt vmcnt(0)" ::: "memory");
        asm volatile("s_barrier" ::: "memory");
    }
#undef STAGEPV

    float* C = Cp + (size_t)bz * sC;
#pragma unroll
    for (int ni = 0; ni < 4; ++ni) {
        const int col = j0 + wc * 64 + ni * 16 + l15;
#pragma unroll
        for (int mi = 0; mi < 4; ++mi) {
            const int rb = i0 + wr * 64 + mi * 16 + g * 4;
#pragma unroll
            for (int r = 0; r < 4; ++r)
                C[(size_t)(rb + r) * N + col] = acc[mi][ni][r];
        }
    }
}

extern "C" void kernel_launch(void* const* d_in, const int* in_sizes, int n_in,
                              void* d_out, int out_size, void* d_ws, size_t ws_size,
                              hipStream_t stream) {
    const float* x  = (const float*)d_in[0];
    const float* Wq = (const float*)d_in[1];
    const float* bq = (const float*)d_in[2];
    const float* Wk = (const float*)d_in[3];
    const float* bk = (const float*)d_in[4];
    float* out = (float*)d_out;

    char* ws = (char*)d_ws;
    unsigned short* xb    = (unsigned short*)(ws);                               // 16 MB
    unsigned short* qk    = (unsigned short*)(ws + (16ull << 20));               // 32 MB [16384][1024]
    unsigned short* WqkT  = (unsigned short*)(ws + (48ull << 20));               // 1 MB [1024][512]
    unsigned short* xsT   = (unsigned short*)(ws + (49ull << 20));               // 16 MB
    float*          s_prt = (float*)(ws + (65ull << 20));                        // 1 MB
    float*          s     = (float*)(ws + (66ull << 20));                        // 64 KB
    unsigned short* expE  = (unsigned short*)(ws + (67ull << 20));               // 64 MB
    if (ws_size < (131ull << 20)) {
        fprintf(stderr, "WS TOO SMALL: have %zu need %llu\n", ws_size, (131ull << 20));
    }

    // 1) xb = bf16(x)
    cast_x_kernel<<<dim3((Bn * Nn * Dn) / (8 * 256)), 256, 0, stream>>>(x, xb, Bn * Nn * Dn);
    // 2) WqkT = bf16([Wq; Wk]^T)  -> [1024][512]
    transpose_cast_kernel<<<dim3(Hn / 64, Dn / 64, 1), 256, 0, stream>>>(Wq, WqkT, nullptr, Dn, Hn);
    transpose_cast_kernel<<<dim3(Hn / 64, Dn / 64, 1), 256, 0, stream>>>(Wk, WqkT + (size_t)Hn * Dn, nullptr, Dn, Hn);
    // 3) qk = xb @ [Wq|Wk] + [bq|bk]   (M=16384, N=1024, K=512) — 4 x 64 = 256 blocks
    {
        const int gx = (2 * Hn) / 256, gy = (Bn * Nn) / 256;
        gemm8p<0><<<dim3(gx * gy), 512, 0, stream>>>(
            xb, 0, Dn, WqkT, 0, Dn, qk, 0, bq, bk, Hn, nullptr,
            Bn * Nn, 2 * Hn, Dn, gx, gy);
    }
    // 4) expE = exp(q @ k^T), s_part (per batch; M=N=2048, K=512) — 8 x 8 x 8 = 512 blocks
    {
        const int gx = Nn / 256, gy = Nn / 256;
        gemm8p<1><<<dim3(gx * gy * Bn), 512, 0, stream>>>(
            qk, (long long)Nn * 2 * Hn, 2 * Hn,               // q = qk[:, 0:512]
            qk + Hn, (long long)Nn * 2 * Hn, 2 * Hn,          // k = qk[:, 512:1024]
            expE, (long long)Nn * Nn, nullptr, nullptr, 0, s_prt,
            Nn, Nn, Hn, gx, gy);
    }
    // 5) s[b][j] = sum of partials (8 m-blocks per batch)
    combine_s_kernel<<<dim3((Bn * Nn) / 256), 256, 0, stream>>>(s_prt, s, Nn / 256, Bn * Nn);
    // 6) xsT[b][d][j] = bf16(x[b][j][d] / s[b][j])
    transpose_cast_kernel<<<dim3(Dn / 64, Nn / 64, Bn), 256, 0, stream>>>(x, xsT, s, Nn, Dn);
    // 7) out = expE @ xsT^T   (per batch; M=2048, N=512, K=2048) — 4 x 16 x 8 = 512 blocks
    {
        const int gx = Dn / 128, gy = Nn / 128;
        gemm_pv<<<dim3(gx * gy * Bn), 256, 0, stream>>>(
            expE, (long long)Nn * Nn, Nn, xsT, (long long)Dn * Nn, Nn,
            out, (long long)Nn * Dn, Nn, Dn, Nn, gx, gy);
    }
}